// Round 1
// baseline (584.884 us; speedup 1.0000x reference)
//
#include <hip/hip_runtime.h>
#include <math.h>

// MoE router: logits -> top-2 -> softmax -> capacity-ranked dispatch.
// Output layout (all float32, concatenated): used_capacity[E], cb_weight[N*E*C], sec_mask[N*E*C].

#define HDIM 1024
#define NEXP 8

// Kernel A: per-token logits (8 dot products of length 1024), top-2 selection,
// softmax over the two selected logits. One wave (64 lanes) per token.
// Writes slot arrays in k-major order: slot s = k*N + n.
__global__ __launch_bounds__(256) void logits_topk_kernel(
    const float* __restrict__ x, const float* __restrict__ wg,
    int* __restrict__ expert_slot, float* __restrict__ prob_slot, int N) {
  __shared__ float w_lds[NEXP * HDIM];  // 32 KB
  const int tid = threadIdx.x;
  for (int i = tid; i < NEXP * HDIM; i += blockDim.x) w_lds[i] = wg[i];
  __syncthreads();

  const int wave = tid >> 6;
  const int lane = tid & 63;
  const int n = blockIdx.x * 4 + wave;
  if (n >= N) return;

  const float* xr = x + (size_t)n * HDIM;
  float acc[NEXP];
#pragma unroll
  for (int e = 0; e < NEXP; e++) acc[e] = 0.0f;

  for (int j = 0; j < HDIM; j += 64) {
    float xv = xr[j + lane];
#pragma unroll
    for (int e = 0; e < NEXP; e++) acc[e] += xv * w_lds[e * HDIM + j + lane];
  }

  // wave tree-reduce each of the 8 partial sums
#pragma unroll
  for (int e = 0; e < NEXP; e++) {
    float v = acc[e];
    for (int off = 32; off > 0; off >>= 1) v += __shfl_down(v, off, 64);
    acc[e] = v;
  }

  if (lane == 0) {
    // top-2, ties -> lower index (matches lax.top_k)
    int b0 = 0;
    float v0 = acc[0];
#pragma unroll
    for (int e = 1; e < NEXP; e++) {
      if (acc[e] > v0) { v0 = acc[e]; b0 = e; }
    }
    int b1 = -1;
    float v1 = -INFINITY;
#pragma unroll
    for (int e = 0; e < NEXP; e++) {
      if (e == b0) continue;
      if (acc[e] > v1) { v1 = acc[e]; b1 = e; }
    }
    // softmax over {v0, v1} (others are -inf -> 0)
    float e2 = expf(v1 - v0);
    float p0 = 1.0f / (1.0f + e2);
    float p1 = e2 / (1.0f + e2);
    expert_slot[n] = b0;
    expert_slot[N + n] = b1;
    prob_slot[n] = p0;
    prob_slot[N + n] = p1;
  }
}

// Kernel B: one block, 8 waves; wave w owns expert w. Scan all S=2N slots in
// order, prefix-count matches via ballot to get exact ranks, scatter nonzeros.
__global__ __launch_bounds__(512) void dispatch_kernel(
    const int* __restrict__ expert_slot, const float* __restrict__ prob_slot,
    float* __restrict__ used_cap, float* __restrict__ cb,
    float* __restrict__ sec, int N, int C) {
  const int w = threadIdx.x >> 6;  // expert id
  const int lane = threadIdx.x & 63;
  if (w >= NEXP) return;

  const int S = 2 * N;
  const unsigned long long below_mask = (lane == 63) ? 0x7FFFFFFFFFFFFFFFull
                                                     : ((1ull << lane) - 1ull);
  int prefix = 0;
  // 4x unrolled: issue 4 independent loads, then 4 dependent ballot steps.
  for (int base = 0; base < S; base += 256) {
    int s0 = base + lane;
    int s1 = base + 64 + lane;
    int s2 = base + 128 + lane;
    int s3 = base + 192 + lane;
    int e0 = expert_slot[s0];
    int e1 = expert_slot[s1];
    int e2 = expert_slot[s2];
    int e3 = expert_slot[s3];
#pragma unroll
    for (int u = 0; u < 4; u++) {
      int s = (u == 0) ? s0 : (u == 1) ? s1 : (u == 2) ? s2 : s3;
      int e = (u == 0) ? e0 : (u == 1) ? e1 : (u == 2) ? e2 : e3;
      bool match = (e == w);
      unsigned long long m = __ballot(match);
      int rank = prefix + __popcll(m & below_mask);
      if (match && rank < C) {
        int n = (s >= N) ? (s - N) : s;
        size_t off = ((size_t)n * NEXP + w) * (size_t)C + (size_t)rank;
        cb[off] = prob_slot[s];
        sec[off] = 1.0f;
      }
      prefix += __popcll(m);
    }
  }
  if (lane == 0) used_cap[w] = (float)(prefix < C ? prefix : C);
}

extern "C" void kernel_launch(void* const* d_in, const int* in_sizes, int n_in,
                              void* d_out, int out_size, void* d_ws, size_t ws_size,
                              hipStream_t stream) {
  const float* x = (const float*)d_in[0];
  const float* wg = (const float*)d_in[1];

  const int N = in_sizes[0] / HDIM;  // 4096 tokens
  const int K = 2;
  int capacity = (int)floor((double)K * 2.0 * (double)N / (double)NEXP);
  if (capacity < 4) capacity = 4;

  float* out = (float*)d_out;
  float* used_cap = out;
  float* cb = out + NEXP;
  float* sec = cb + (size_t)N * NEXP * (size_t)capacity;

  int* expert_slot = (int*)d_ws;
  float* prob_slot = (float*)((char*)d_ws + sizeof(int) * (size_t)(2 * N));

  // Zero the (poisoned) 537 MB output — the dominant, unavoidable cost.
  hipMemsetAsync(d_out, 0, sizeof(float) * (size_t)out_size, stream);

  logits_topk_kernel<<<(N + 3) / 4, 256, 0, stream>>>(x, wg, expert_slot,
                                                      prob_slot, N);
  dispatch_kernel<<<1, 512, 0, stream>>>(expert_slot, prob_slot, used_cap, cb,
                                         sec, N, capacity);
}